// Round 1
// baseline (4358.382 us; speedup 1.0000x reference)
//
#include <hip/hip_runtime.h>

#define N_NODES 100000
#define N_EDGES 1600000
#define EMBED 64

// ---------------- degree / dinv ----------------
__global__ void deg_kernel(const int* __restrict__ dst, float* __restrict__ deg) {
    int e = blockIdx.x * blockDim.x + threadIdx.x;
    if (e < N_EDGES) atomicAdd(&deg[dst[e]], 1.0f);
}

__global__ void dinv_kernel(float* __restrict__ deg) {
    int i = blockIdx.x * blockDim.x + threadIdx.x;
    if (i < N_NODES) deg[i] = rsqrtf(deg[i] + 1.0f);
}

// ---------------- dense GEMM: Y[N,64] = X[N,64] @ W[64,64] ----------------
__global__ __launch_bounds__(256) void gemm_kernel(const float* __restrict__ X,
                                                   const float* __restrict__ W,
                                                   float* __restrict__ Y) {
    __shared__ float sW[64 * 64];
    __shared__ float sX[32 * 64];
    int tid = threadIdx.x;
    for (int i = tid; i < 64 * 64; i += 256) sW[i] = W[i];
    int row0 = blockIdx.x * 32;
    for (int i = tid; i < 32 * 64; i += 256) {
        int r = i >> 6, c = i & 63;
        int gr = row0 + r;
        sX[i] = (gr < N_NODES) ? X[gr * 64 + c] : 0.0f;
    }
    __syncthreads();
    int col = tid & 63;
    int rg = tid >> 6;  // 0..3, each handles 8 rows
    float acc[8];
#pragma unroll
    for (int j = 0; j < 8; j++) acc[j] = 0.0f;
    for (int k = 0; k < 64; k++) {
        float w = sW[k * 64 + col];
#pragma unroll
        for (int j = 0; j < 8; j++) acc[j] += sX[(rg * 8 + j) * 64 + k] * w;
    }
#pragma unroll
    for (int j = 0; j < 8; j++) {
        int gr = row0 + rg * 8 + j;
        if (gr < N_NODES) Y[gr * 64 + col] = acc[j];
    }
}

// ---------------- out init: self-loop term + bias ----------------
__global__ void init_out_kernel(const float* __restrict__ Y, const float* __restrict__ dinv,
                                const float* __restrict__ b, float* __restrict__ out) {
    int i = blockIdx.x * blockDim.x + threadIdx.x;
    if (i < N_NODES * EMBED) {
        int node = i >> 6, c = i & 63;
        float di = dinv[node];
        out[i] = Y[i] * di * di + b[c];
    }
}

// ---------------- edge scatter: out[dst] += Y[src] * dinv[src]*dinv[dst] ----------------
__global__ __launch_bounds__(256) void scatter_kernel(const int* __restrict__ src,
                                                      const int* __restrict__ dst,
                                                      const float* __restrict__ dinv,
                                                      const float* __restrict__ Y,
                                                      float* __restrict__ out) {
    int gid = blockIdx.x * blockDim.x + threadIdx.x;
    int e = gid >> 4;  // 16 threads per edge, 4 channels each
    if (e >= N_EDGES) return;
    int q = (gid & 15) * 4;
    int s = src[e], d = dst[e];
    float norm = dinv[s] * dinv[d];
    const float4 v = *(const float4*)(Y + (size_t)s * EMBED + q);
    float* o = out + (size_t)d * EMBED + q;
    atomicAdd(o + 0, v.x * norm);
    atomicAdd(o + 1, v.y * norm);
    atomicAdd(o + 2, v.z * norm);
    atomicAdd(o + 3, v.w * norm);
}

extern "C" void kernel_launch(void* const* d_in, const int* in_sizes, int n_in,
                              void* d_out, int out_size, void* d_ws, size_t ws_size,
                              hipStream_t stream) {
    const float* emb = (const float*)d_in[0];
    const int* edge  = (const int*)d_in[1];
    const float* W1 = (const float*)d_in[2];
    const float* b1 = (const float*)d_in[3];
    const float* W2 = (const float*)d_in[4];
    const float* b2 = (const float*)d_in[5];
    const float* W3 = (const float*)d_in[6];
    const float* b3 = (const float*)d_in[7];
    float* out = (float*)d_out;

    const int* src = edge;
    const int* dst = edge + N_EDGES;

    char* ws = (char*)d_ws;
    float* dinv = (float*)ws;                       // N_NODES floats (400000 B)
    float* Y = (float*)(ws + 400128);               // 25.6 MB
    float* X = (float*)(ws + 400128 + 25600000);    // 25.6 MB

    // degrees (shared across all 3 layers)
    hipMemsetAsync(dinv, 0, N_NODES * sizeof(float), stream);
    deg_kernel<<<(N_EDGES + 255) / 256, 256, 0, stream>>>(dst, dinv);
    dinv_kernel<<<(N_NODES + 255) / 256, 256, 0, stream>>>(dinv);

    const int gemm_grid = (N_NODES + 31) / 32;
    const int elem_grid = (N_NODES * EMBED + 255) / 256;
    const int scat_grid = (N_EDGES * 16 + 255) / 256;

    // layer 1: emb -> X
    gemm_kernel<<<gemm_grid, 256, 0, stream>>>(emb, W1, Y);
    init_out_kernel<<<elem_grid, 256, 0, stream>>>(Y, dinv, b1, X);
    scatter_kernel<<<scat_grid, 256, 0, stream>>>(src, dst, dinv, Y, X);

    // layer 2: X -> X (via Y)
    gemm_kernel<<<gemm_grid, 256, 0, stream>>>(X, W2, Y);
    init_out_kernel<<<elem_grid, 256, 0, stream>>>(Y, dinv, b2, X);
    scatter_kernel<<<scat_grid, 256, 0, stream>>>(src, dst, dinv, Y, X);

    // layer 3: X -> d_out
    gemm_kernel<<<gemm_grid, 256, 0, stream>>>(X, W3, Y);
    init_out_kernel<<<elem_grid, 256, 0, stream>>>(Y, dinv, b3, out);
    scatter_kernel<<<scat_grid, 256, 0, stream>>>(src, dst, dinv, Y, out);
}

// Round 2
// 634.630 us; speedup vs baseline: 6.8676x; 6.8676x over previous
//
#include <hip/hip_runtime.h>

#define N_NODES 100000
#define N_EDGES 1600000
#define EMBED 64
#define SCAN_B 256
#define N_SCAN_BLOCKS ((N_NODES + SCAN_B - 1) / SCAN_B)  // 391

// ---------------- degree histogram ----------------
__global__ void hist_kernel(const int* __restrict__ dst, int* __restrict__ cnt) {
    int e = blockIdx.x * blockDim.x + threadIdx.x;
    if (e < N_EDGES) atomicAdd(&cnt[dst[e]], 1);
}

__global__ void dinv_kernel(const int* __restrict__ cnt, float* __restrict__ dinv) {
    int i = blockIdx.x * blockDim.x + threadIdx.x;
    if (i < N_NODES) dinv[i] = rsqrtf((float)cnt[i] + 1.0f);
}

// ---------------- 2-level exclusive scan of cnt -> offs ----------------
__global__ void block_sum_kernel(const int* __restrict__ cnt, int* __restrict__ bsum) {
    __shared__ int s[SCAN_B];
    int i = blockIdx.x * SCAN_B + threadIdx.x;
    s[threadIdx.x] = (i < N_NODES) ? cnt[i] : 0;
    __syncthreads();
    for (int off = SCAN_B / 2; off > 0; off >>= 1) {
        if (threadIdx.x < off) s[threadIdx.x] += s[threadIdx.x + off];
        __syncthreads();
    }
    if (threadIdx.x == 0) bsum[blockIdx.x] = s[0];
}

__global__ void scan_bsum_kernel(int* __restrict__ bsum) {
    // single block of 512, Hillis-Steele, nb = N_SCAN_BLOCKS < 512
    __shared__ int s[512];
    int t = threadIdx.x;
    s[t] = (t < N_SCAN_BLOCKS) ? bsum[t] : 0;
    __syncthreads();
    for (int off = 1; off < 512; off <<= 1) {
        int v = (t >= off) ? s[t - off] : 0;
        __syncthreads();
        s[t] += v;
        __syncthreads();
    }
    if (t < N_SCAN_BLOCKS) bsum[t] = (t == 0) ? 0 : s[t - 1];  // exclusive
}

__global__ void scan_offsets_kernel(const int* __restrict__ cnt, const int* __restrict__ bsum,
                                    int* __restrict__ offs) {
    __shared__ int s[SCAN_B];
    int i = blockIdx.x * SCAN_B + threadIdx.x;
    int v = (i < N_NODES) ? cnt[i] : 0;
    s[threadIdx.x] = v;
    __syncthreads();
    for (int off = 1; off < SCAN_B; off <<= 1) {
        int u = (threadIdx.x >= off) ? s[threadIdx.x - off] : 0;
        __syncthreads();
        s[threadIdx.x] += u;
        __syncthreads();
    }
    int incl = s[threadIdx.x];
    if (i < N_NODES) offs[i] = incl - v + bsum[blockIdx.x];
    if (i == N_NODES - 1) offs[N_NODES] = incl + bsum[blockIdx.x];
}

// ---------------- CSR fill ----------------
__global__ void fill_kernel(const int* __restrict__ src, const int* __restrict__ dst,
                            const int* __restrict__ offs, int* __restrict__ cursor,
                            int* __restrict__ csr_src) {
    int e = blockIdx.x * blockDim.x + threadIdx.x;
    if (e < N_EDGES) {
        int d = dst[e];
        int pos = atomicAdd(&cursor[d], 1);
        csr_src[offs[d] + pos] = src[e];
    }
}

// ---------------- dense GEMM: Y[N,64] = X[N,64] @ W[64,64] ----------------
__global__ __launch_bounds__(256) void gemm_kernel(const float* __restrict__ X,
                                                   const float* __restrict__ W,
                                                   float* __restrict__ Y) {
    __shared__ float sW[64 * 64];
    __shared__ float sX[32 * 64];
    int tid = threadIdx.x;
    for (int i = tid; i < 64 * 64; i += 256) sW[i] = W[i];
    int row0 = blockIdx.x * 32;
    for (int i = tid; i < 32 * 64; i += 256) {
        int r = i >> 6, c = i & 63;
        int gr = row0 + r;
        sX[i] = (gr < N_NODES) ? X[gr * 64 + c] : 0.0f;
    }
    __syncthreads();
    int col = tid & 63;
    int rg = tid >> 6;
    float acc[8];
#pragma unroll
    for (int j = 0; j < 8; j++) acc[j] = 0.0f;
    for (int k = 0; k < 64; k++) {
        float w = sW[k * 64 + col];
#pragma unroll
        for (int j = 0; j < 8; j++) acc[j] += sX[(rg * 8 + j) * 64 + k] * w;
    }
#pragma unroll
    for (int j = 0; j < 8; j++) {
        int gr = row0 + rg * 8 + j;
        if (gr < N_NODES) Y[gr * 64 + col] = acc[j];
    }
}

// ---------------- gather: out[n] = sum_{s in in(n)} Y[s]*dinv[s]*dinv[n] + Y[n]*dinv[n]^2 + b
__global__ __launch_bounds__(256) void gather_kernel(const float* __restrict__ Y,
                                                     const float* __restrict__ dinv,
                                                     const int* __restrict__ offs,
                                                     const int* __restrict__ csr_src,
                                                     const float* __restrict__ b,
                                                     float* __restrict__ out) {
    int node = (blockIdx.x * blockDim.x + threadIdx.x) >> 6;
    int lane = threadIdx.x & 63;
    if (node >= N_NODES) return;
    float di = dinv[node];
    float acc = Y[(size_t)node * EMBED + lane] * di * di + b[lane];
    int beg = offs[node], end = offs[node + 1];
    int i = beg;
    for (; i + 1 < end; i += 2) {
        int s0 = csr_src[i], s1 = csr_src[i + 1];
        float n0 = dinv[s0] * di, n1 = dinv[s1] * di;
        float v0 = Y[(size_t)s0 * EMBED + lane];
        float v1 = Y[(size_t)s1 * EMBED + lane];
        acc += v0 * n0 + v1 * n1;
    }
    if (i < end) {
        int s = csr_src[i];
        acc += Y[(size_t)s * EMBED + lane] * (dinv[s] * di);
    }
    out[(size_t)node * EMBED + lane] = acc;
}

extern "C" void kernel_launch(void* const* d_in, const int* in_sizes, int n_in,
                              void* d_out, int out_size, void* d_ws, size_t ws_size,
                              hipStream_t stream) {
    const float* emb = (const float*)d_in[0];
    const int* edge  = (const int*)d_in[1];
    const float* W1 = (const float*)d_in[2];
    const float* b1 = (const float*)d_in[3];
    const float* W2 = (const float*)d_in[4];
    const float* b2 = (const float*)d_in[5];
    const float* W3 = (const float*)d_in[6];
    const float* b3 = (const float*)d_in[7];
    float* out = (float*)d_out;

    const int* src = edge;
    const int* dst = edge + N_EDGES;

    char* ws = (char*)d_ws;
    size_t off = 0;
    int* cnt = (int*)(ws + off);      off += 400128;
    int* offs = (int*)(ws + off);     off += 400128;   // N_NODES+1
    int* cursor = (int*)(ws + off);   off += 400128;
    int* bsum = (int*)(ws + off);     off += 2048;
    float* dinv = (float*)(ws + off); off += 400128;
    int* csr_src = (int*)(ws + off);  off += 6400128;
    float* Y = (float*)(ws + off);    off += 25600000;
    float* X = (float*)(ws + off);    // 25.6 MB

    // ---- CSR build (once; shared by all 3 layers) ----
    hipMemsetAsync(cnt, 0, N_NODES * sizeof(int), stream);
    hipMemsetAsync(cursor, 0, N_NODES * sizeof(int), stream);
    hist_kernel<<<(N_EDGES + 255) / 256, 256, 0, stream>>>(dst, cnt);
    dinv_kernel<<<(N_NODES + 255) / 256, 256, 0, stream>>>(cnt, dinv);
    block_sum_kernel<<<N_SCAN_BLOCKS, SCAN_B, 0, stream>>>(cnt, bsum);
    scan_bsum_kernel<<<1, 512, 0, stream>>>(bsum);
    scan_offsets_kernel<<<N_SCAN_BLOCKS, SCAN_B, 0, stream>>>(cnt, bsum, offs);
    fill_kernel<<<(N_EDGES + 255) / 256, 256, 0, stream>>>(src, dst, offs, cursor, csr_src);

    const int gemm_grid = (N_NODES + 31) / 32;
    const int gather_grid = (N_NODES * 64 + 255) / 256;  // 1 wave per node

    // layer 1: emb -> X
    gemm_kernel<<<gemm_grid, 256, 0, stream>>>(emb, W1, Y);
    gather_kernel<<<gather_grid, 256, 0, stream>>>(Y, dinv, offs, csr_src, b1, X);

    // layer 2: X -> X
    gemm_kernel<<<gemm_grid, 256, 0, stream>>>(X, W2, Y);
    gather_kernel<<<gather_grid, 256, 0, stream>>>(Y, dinv, offs, csr_src, b2, X);

    // layer 3: X -> out
    gemm_kernel<<<gemm_grid, 256, 0, stream>>>(X, W3, Y);
    gather_kernel<<<gather_grid, 256, 0, stream>>>(Y, dinv, offs, csr_src, b3, out);
}

// Round 3
// 526.394 us; speedup vs baseline: 8.2797x; 1.2056x over previous
//
#include <hip/hip_runtime.h>

#define N_NODES 100000
#define N_EDGES 1600000
#define SCAN_B 256
#define N_SCAN_BLOCKS ((N_NODES + SCAN_B - 1) / SCAN_B)  // 391

// ---------------- degree histogram ----------------
__global__ void hist_kernel(const int* __restrict__ dst, int* __restrict__ cnt) {
    int e = blockIdx.x * blockDim.x + threadIdx.x;
    if (e < N_EDGES) atomicAdd(&cnt[dst[e]], 1);
}

// ---------------- 2-level exclusive scan of cnt -> offs (+ dinv + cursor seed) ----------------
__global__ void block_sum_kernel(const int* __restrict__ cnt, int* __restrict__ bsum) {
    __shared__ int s[SCAN_B];
    int i = blockIdx.x * SCAN_B + threadIdx.x;
    s[threadIdx.x] = (i < N_NODES) ? cnt[i] : 0;
    __syncthreads();
    for (int off = SCAN_B / 2; off > 0; off >>= 1) {
        if (threadIdx.x < off) s[threadIdx.x] += s[threadIdx.x + off];
        __syncthreads();
    }
    if (threadIdx.x == 0) bsum[blockIdx.x] = s[0];
}

__global__ void scan_bsum_kernel(int* __restrict__ bsum) {
    __shared__ int s[512];
    int t = threadIdx.x;
    s[t] = (t < N_SCAN_BLOCKS) ? bsum[t] : 0;
    __syncthreads();
    for (int off = 1; off < 512; off <<= 1) {
        int v = (t >= off) ? s[t - off] : 0;
        __syncthreads();
        s[t] += v;
        __syncthreads();
    }
    if (t < N_SCAN_BLOCKS) bsum[t] = (t == 0) ? 0 : s[t - 1];  // exclusive
}

__global__ void scan_offsets_kernel(const int* __restrict__ cnt, const int* __restrict__ bsum,
                                    int* __restrict__ offs, int* __restrict__ cursor,
                                    float* __restrict__ dinv) {
    __shared__ int s[SCAN_B];
    int i = blockIdx.x * SCAN_B + threadIdx.x;
    int v = (i < N_NODES) ? cnt[i] : 0;
    s[threadIdx.x] = v;
    __syncthreads();
    for (int off = 1; off < SCAN_B; off <<= 1) {
        int u = (threadIdx.x >= off) ? s[threadIdx.x - off] : 0;
        __syncthreads();
        s[threadIdx.x] += u;
        __syncthreads();
    }
    int incl = s[threadIdx.x];
    if (i < N_NODES) {
        int o = incl - v + bsum[blockIdx.x];
        offs[i] = o;
        cursor[i] = o;                       // fill uses cursor directly as slot
        dinv[i] = rsqrtf((float)v + 1.0f);   // fold dinv here (cnt already loaded)
    }
    if (i == N_NODES - 1) offs[N_NODES] = incl + bsum[blockIdx.x];
}

// ---------------- CSR fill: entry = (src, dinv[src]) ----------------
__global__ void fill_kernel(const int* __restrict__ src, const int* __restrict__ dst,
                            const float* __restrict__ dinv,
                            int* __restrict__ cursor, int2* __restrict__ csr) {
    int e = blockIdx.x * blockDim.x + threadIdx.x;
    if (e < N_EDGES) {
        int s = src[e];
        int pos = atomicAdd(&cursor[dst[e]], 1);
        csr[pos] = make_int2(s, __float_as_int(dinv[s]));
    }
}

// ---------------- fused gather + GEMM epilogue ----------------
// out[n] = (sum_{s in in(n)} X[s]*dinv[s]*dinv[n] + X[n]*dinv[n]^2) @ W + b
__global__ __launch_bounds__(256) void gather_fused_kernel(
    const float* __restrict__ X, const float* __restrict__ dinv,
    const int* __restrict__ offs, const int2* __restrict__ csr,
    const float* __restrict__ W, const float* __restrict__ b,
    float* __restrict__ out, int n_waves) {
    int lane = threadIdx.x & 63;
    int wid = __builtin_amdgcn_readfirstlane((int)((blockIdx.x * blockDim.x + threadIdx.x) >> 6));

    // W column for this lane, held in VGPRs; amortized over ~N_NODES/n_waves nodes
    float wcol[64];
#pragma unroll
    for (int k = 0; k < 64; k++) wcol[k] = W[k * 64 + lane];
    float blane = b[lane];

    for (int node = wid; node < N_NODES; node += n_waves) {
        float di = dinv[node];
        float acc = X[(size_t)node * 64 + lane] * di * di;
        int beg = offs[node], end = offs[node + 1];
        int i = beg;
        for (; i + 3 < end; i += 4) {
            int2 e0 = csr[i], e1 = csr[i + 1], e2 = csr[i + 2], e3 = csr[i + 3];
            float r0 = X[(size_t)e0.x * 64 + lane];
            float r1 = X[(size_t)e1.x * 64 + lane];
            float r2 = X[(size_t)e2.x * 64 + lane];
            float r3 = X[(size_t)e3.x * 64 + lane];
            acc += r0 * (__int_as_float(e0.y) * di);
            acc += r1 * (__int_as_float(e1.y) * di);
            acc += r2 * (__int_as_float(e2.y) * di);
            acc += r3 * (__int_as_float(e3.y) * di);
        }
        for (; i < end; i++) {
            int2 e0 = csr[i];
            acc += X[(size_t)e0.x * 64 + lane] * (__int_as_float(e0.y) * di);
        }
        // matvec epilogue: r[c] = sum_k acc_k * W[k][c] + b[c]
        float r = blane;
#pragma unroll
        for (int k = 0; k < 64; k++) {
            float ak = __int_as_float(__builtin_amdgcn_readlane(__float_as_int(acc), k));
            r += ak * wcol[k];
        }
        out[(size_t)node * 64 + lane] = r;
    }
}

extern "C" void kernel_launch(void* const* d_in, const int* in_sizes, int n_in,
                              void* d_out, int out_size, void* d_ws, size_t ws_size,
                              hipStream_t stream) {
    const float* emb = (const float*)d_in[0];
    const int* edge  = (const int*)d_in[1];
    const float* W1 = (const float*)d_in[2];
    const float* b1 = (const float*)d_in[3];
    const float* W2 = (const float*)d_in[4];
    const float* b2 = (const float*)d_in[5];
    const float* W3 = (const float*)d_in[6];
    const float* b3 = (const float*)d_in[7];
    float* out = (float*)d_out;

    const int* src = edge;
    const int* dst = edge + N_EDGES;

    char* ws = (char*)d_ws;
    size_t off = 0;
    int* cnt = (int*)(ws + off);      off += 400128;
    int* offs = (int*)(ws + off);     off += 400128;   // N_NODES+1
    int* cursor = (int*)(ws + off);   off += 400128;
    int* bsum = (int*)(ws + off);     off += 2048;
    float* dinv = (float*)(ws + off); off += 400128;
    int2* csr = (int2*)(ws + off);    off += 12800128; // 1.6M * 8B
    float* Xa = (float*)(ws + off);   off += 25600000;
    float* Xb = (float*)(ws + off);   // 25.6 MB

    // ---- CSR build (shared by all 3 layers) ----
    hipMemsetAsync(cnt, 0, N_NODES * sizeof(int), stream);
    hist_kernel<<<(N_EDGES + 255) / 256, 256, 0, stream>>>(dst, cnt);
    block_sum_kernel<<<N_SCAN_BLOCKS, SCAN_B, 0, stream>>>(cnt, bsum);
    scan_bsum_kernel<<<1, 512, 0, stream>>>(bsum);
    scan_offsets_kernel<<<N_SCAN_BLOCKS, SCAN_B, 0, stream>>>(cnt, bsum, offs, cursor, dinv);
    fill_kernel<<<(N_EDGES + 255) / 256, 256, 0, stream>>>(src, dst, dinv, cursor, csr);

    const int GBLOCKS = 1024;                 // 4096 waves, ~25 nodes each
    const int n_waves = GBLOCKS * 256 / 64;

    // layer 1: emb -> Xa
    gather_fused_kernel<<<GBLOCKS, 256, 0, stream>>>(emb, dinv, offs, csr, W1, b1, Xa, n_waves);
    // layer 2: Xa -> Xb
    gather_fused_kernel<<<GBLOCKS, 256, 0, stream>>>(Xa, dinv, offs, csr, W2, b2, Xb, n_waves);
    // layer 3: Xb -> out
    gather_fused_kernel<<<GBLOCKS, 256, 0, stream>>>(Xb, dinv, offs, csr, W3, b3, out, n_waves);
}

// Round 4
// 411.546 us; speedup vs baseline: 10.5903x; 1.2791x over previous
//
#include <hip/hip_runtime.h>

#define N_NODES 100000
#define N_EDGES 1600000
#define SCAN_B 256
#define N_SCAN_BLOCKS ((N_NODES + SCAN_B - 1) / SCAN_B)  // 391

#define BKT_SHIFT 8
#define BKT_NODES 256
#define NBK ((N_NODES + BKT_NODES - 1) / BKT_NODES)      // 391 buckets
#define CHUNK 4096
#define NCHUNKS ((N_EDGES + CHUNK - 1) / CHUNK)          // 391 chunks
#define BCAP 6144                                        // LDS cap per bucket (avg 4096, ~32 sigma)

// ---------------- degree histogram ----------------
__global__ void hist_kernel(const int* __restrict__ dst, int* __restrict__ cnt) {
    int e = blockIdx.x * blockDim.x + threadIdx.x;
    if (e < N_EDGES) atomicAdd(&cnt[dst[e]], 1);
}

// ---------------- 2-level exclusive scan ----------------
__global__ void block_sum_kernel(const int* __restrict__ cnt, int* __restrict__ bsum) {
    __shared__ int s[SCAN_B];
    int i = blockIdx.x * SCAN_B + threadIdx.x;
    s[threadIdx.x] = (i < N_NODES) ? cnt[i] : 0;
    __syncthreads();
    for (int off = SCAN_B / 2; off > 0; off >>= 1) {
        if (threadIdx.x < off) s[threadIdx.x] += s[threadIdx.x + off];
        __syncthreads();
    }
    if (threadIdx.x == 0) bsum[blockIdx.x] = s[0];
}

__global__ void scan_bsum_kernel(int* __restrict__ bsum) {
    __shared__ int s[512];
    int t = threadIdx.x;
    s[t] = (t < N_SCAN_BLOCKS) ? bsum[t] : 0;
    __syncthreads();
    for (int off = 1; off < 512; off <<= 1) {
        int v = (t >= off) ? s[t - off] : 0;
        __syncthreads();
        s[t] += v;
        __syncthreads();
    }
    if (t < N_SCAN_BLOCKS) bsum[t] = (t == 0) ? 0 : s[t - 1];  // exclusive
}

// offs + cursor(seed=offs, for fallback) + dinv + per-bucket base cursors
__global__ void scan_offsets_kernel(const int* __restrict__ cnt, const int* __restrict__ bsum,
                                    int* __restrict__ offs, int* __restrict__ cursor,
                                    float* __restrict__ dinv, int* __restrict__ bcursor) {
    __shared__ int s[SCAN_B];
    int i = blockIdx.x * SCAN_B + threadIdx.x;
    int v = (i < N_NODES) ? cnt[i] : 0;
    s[threadIdx.x] = v;
    __syncthreads();
    for (int off = 1; off < SCAN_B; off <<= 1) {
        int u = (threadIdx.x >= off) ? s[threadIdx.x - off] : 0;
        __syncthreads();
        s[threadIdx.x] += u;
        __syncthreads();
    }
    int incl = s[threadIdx.x];
    if (i < N_NODES) {
        int o = incl - v + bsum[blockIdx.x];
        offs[i] = o;
        cursor[i] = o;
        dinv[i] = rsqrtf((float)v + 1.0f);
        if ((i & (BKT_NODES - 1)) == 0) bcursor[i >> BKT_SHIFT] = o;  // bucket base
    }
    if (i == N_NODES - 1) offs[N_NODES] = incl + bsum[blockIdx.x];
}

// ---------------- phase A: bin edges by 256-node bucket, coalesced runs ----------------
__global__ __launch_bounds__(512) void binA_kernel(const int* __restrict__ src,
                                                   const int* __restrict__ dst,
                                                   int* __restrict__ bcursor,
                                                   int2* __restrict__ csr_tmp) {
    __shared__ int2 staged[CHUNK];   // 32 KB
    __shared__ int delta[CHUNK];     // 16 KB
    __shared__ int hist[NBK];
    __shared__ int lcur[NBK];
    __shared__ int gdel[NBK];
    __shared__ int scan_s[512];
    int t = threadIdx.x;
    int e0 = blockIdx.x * CHUNK;
    int n = N_EDGES - e0; if (n > CHUNK) n = CHUNK;

    for (int i = t; i < NBK; i += 512) hist[i] = 0;
    __syncthreads();
    for (int i = t; i < n; i += 512) atomicAdd(&hist[dst[e0 + i] >> BKT_SHIFT], 1);
    __syncthreads();
    // scan the bucket histogram (NBK < 512)
    int v = (t < NBK) ? hist[t] : 0;
    scan_s[t] = v;
    __syncthreads();
    for (int off = 1; off < 512; off <<= 1) {
        int u = (t >= off) ? scan_s[t - off] : 0;
        __syncthreads();
        scan_s[t] += u;
        __syncthreads();
    }
    if (t < NBK) {
        int excl = scan_s[t] - v;
        lcur[t] = excl;
        int g = atomicAdd(&bcursor[t], v);  // reserve contiguous run in bucket region
        gdel[t] = g - excl;
    }
    __syncthreads();
    // scatter chunk into LDS, ordered by bucket
    for (int i = t; i < n; i += 512) {
        int s = src[e0 + i];
        int d = dst[e0 + i];
        int bkt = d >> BKT_SHIFT;
        int slot = atomicAdd(&lcur[bkt], 1);
        staged[slot] = make_int2(s, d);
        delta[slot] = gdel[bkt];
    }
    __syncthreads();
    // stream out: coalesced runs per bucket segment
    for (int p = t; p < n; p += 512) {
        csr_tmp[delta[p] + p] = staged[p];
    }
}

// ---------------- phase B: per-bucket exact CSR ordering in LDS ----------------
__global__ __launch_bounds__(256) void binB_kernel(const int* __restrict__ offs,
                                                   const float* __restrict__ dinv,
                                                   int* __restrict__ cursor,
                                                   const int2* __restrict__ csr_tmp,
                                                   int2* __restrict__ csr) {
    __shared__ int2 staged[BCAP];    // 48 KB
    __shared__ int lcur[BKT_NODES];
    int t = threadIdx.x;
    int node0 = blockIdx.x * BKT_NODES;
    int node1 = node0 + BKT_NODES; if (node1 > N_NODES) node1 = N_NODES;
    int base = offs[node0];
    int cnt = offs[node1] - base;
    if (node0 + t < node1) lcur[t] = offs[node0 + t] - base;
    __syncthreads();
    if (cnt <= BCAP) {
        for (int i = t; i < cnt; i += 256) {
            int2 e = csr_tmp[base + i];              // (src, dst)
            float w = dinv[e.x];
            int slot = atomicAdd(&lcur[e.y - node0], 1);
            staged[slot] = make_int2(e.x, __float_as_int(w));
        }
        __syncthreads();
        for (int i = t; i < cnt; i += 256) csr[base + i] = staged[i];
    } else {
        // statistically unreachable fallback (safe: distinct src/dst buffers)
        for (int i = t; i < cnt; i += 256) {
            int2 e = csr_tmp[base + i];
            float w = dinv[e.x];
            int slot = atomicAdd(&cursor[e.y], 1);
            csr[slot] = make_int2(e.x, __float_as_int(w));
        }
    }
}

// ---------------- fused gather + GEMM epilogue ----------------
// out[n] = (sum_{s in in(n)} X[s]*dinv[s]*dinv[n] + X[n]*dinv[n]^2) @ W + b
__global__ __launch_bounds__(256) void gather_fused_kernel(
    const float* __restrict__ X, const float* __restrict__ dinv,
    const int* __restrict__ offs, const int2* __restrict__ csr,
    const float* __restrict__ W, const float* __restrict__ b,
    float* __restrict__ out, int n_waves) {
    int lane = threadIdx.x & 63;
    int wid = (blockIdx.x * blockDim.x + threadIdx.x) >> 6;
    int sub = lane >> 4;       // 0..3: edge slot within wave
    int l16 = lane & 15;       // 4-channel group: channels l16*4..+3
    const float4* Xv = (const float4*)X;

    float wcol[64];            // W[k][lane] for epilogue (lane = output channel)
#pragma unroll
    for (int k = 0; k < 64; k++) wcol[k] = W[k * 64 + lane];
    float blane = b[lane];

    for (int node = wid; node < N_NODES; node += n_waves) {
        float di = dinv[node];
        int beg = offs[node], end = offs[node + 1];
        float4 acc;
        if (sub == 0) {
            float4 xs = Xv[node * 16 + l16];
            float d2 = di * di;
            acc = make_float4(xs.x * d2, xs.y * d2, xs.z * d2, xs.w * d2);
        } else {
            acc = make_float4(0.f, 0.f, 0.f, 0.f);
        }
        // 4 edges in flight per wave (one per sub); depth-2 csr prefetch
        int i = beg + sub;
        int2 e0 = (i < end) ? csr[i] : make_int2(0, 0);
        int2 e1 = (i + 4 < end) ? csr[i + 4] : make_int2(0, 0);
        while (i < end) {
            float nw = __int_as_float(e0.y) * di;
            float4 vr = Xv[e0.x * 16 + l16];
            int inn = i + 8;
            int2 e2 = (inn < end) ? csr[inn] : make_int2(0, 0);
            acc.x += vr.x * nw;
            acc.y += vr.y * nw;
            acc.z += vr.z * nw;
            acc.w += vr.w * nw;
            e0 = e1; e1 = e2; i += 4;
        }
        // reduce across the 4 subs (xor 16, 32)
        acc.x += __shfl_xor(acc.x, 16, 64); acc.y += __shfl_xor(acc.y, 16, 64);
        acc.z += __shfl_xor(acc.z, 16, 64); acc.w += __shfl_xor(acc.w, 16, 64);
        acc.x += __shfl_xor(acc.x, 32, 64); acc.y += __shfl_xor(acc.y, 32, 64);
        acc.z += __shfl_xor(acc.z, 32, 64); acc.w += __shfl_xor(acc.w, 32, 64);
        // redistribute: lane c takes channel c = (c>>2)*4 + (c&3)
        int srcl = lane >> 2;
        float t0 = __shfl(acc.x, srcl, 64);
        float t1 = __shfl(acc.y, srcl, 64);
        float t2 = __shfl(acc.z, srcl, 64);
        float t3 = __shfl(acc.w, srcl, 64);
        int comp = lane & 3;
        float a = (comp == 0) ? t0 : (comp == 1) ? t1 : (comp == 2) ? t2 : t3;
        // matvec epilogue: r[c] = b[c] + sum_k a_k * W[k][c]
        float r = blane;
#pragma unroll
        for (int k = 0; k < 64; k++) {
            float ak = __int_as_float(__builtin_amdgcn_readlane(__float_as_int(a), k));
            r += ak * wcol[k];
        }
        out[(size_t)node * 64 + lane] = r;
    }
}

extern "C" void kernel_launch(void* const* d_in, const int* in_sizes, int n_in,
                              void* d_out, int out_size, void* d_ws, size_t ws_size,
                              hipStream_t stream) {
    const float* emb = (const float*)d_in[0];
    const int* edge  = (const int*)d_in[1];
    const float* W1 = (const float*)d_in[2];
    const float* b1 = (const float*)d_in[3];
    const float* W2 = (const float*)d_in[4];
    const float* b2 = (const float*)d_in[5];
    const float* W3 = (const float*)d_in[6];
    const float* b3 = (const float*)d_in[7];
    float* out = (float*)d_out;

    const int* src = edge;
    const int* dst = edge + N_EDGES;

    char* ws = (char*)d_ws;
    size_t off = 0;
    int* cnt = (int*)(ws + off);        off += 400128;
    int* offs = (int*)(ws + off);       off += 400128;   // N_NODES+1
    int* cursor = (int*)(ws + off);     off += 400128;
    int* bsum = (int*)(ws + off);       off += 2048;
    int* bcursor = (int*)(ws + off);    off += 2048;     // NBK
    float* dinv = (float*)(ws + off);   off += 400128;
    int2* csr_tmp = (int2*)(ws + off);  off += 12800128;
    int2* csr = (int2*)(ws + off);      off += 12800128;
    float* Xa = (float*)(ws + off);     off += 25600000;
    float* Xb = (float*)(ws + off);     // 25.6 MB

    // ---- CSR build (shared by all 3 layers) ----
    hipMemsetAsync(cnt, 0, N_NODES * sizeof(int), stream);
    hist_kernel<<<(N_EDGES + 255) / 256, 256, 0, stream>>>(dst, cnt);
    block_sum_kernel<<<N_SCAN_BLOCKS, SCAN_B, 0, stream>>>(cnt, bsum);
    scan_bsum_kernel<<<1, 512, 0, stream>>>(bsum);
    scan_offsets_kernel<<<N_SCAN_BLOCKS, SCAN_B, 0, stream>>>(cnt, bsum, offs, cursor, dinv, bcursor);
    binA_kernel<<<NCHUNKS, 512, 0, stream>>>(src, dst, bcursor, csr_tmp);
    binB_kernel<<<NBK, 256, 0, stream>>>(offs, dinv, cursor, csr_tmp, csr);

    const int GBLOCKS = 1280;                 // 5120 waves, ~20 nodes each
    const int n_waves = GBLOCKS * 256 / 64;

    gather_fused_kernel<<<GBLOCKS, 256, 0, stream>>>(emb, dinv, offs, csr, W1, b1, Xa, n_waves);
    gather_fused_kernel<<<GBLOCKS, 256, 0, stream>>>(Xa, dinv, offs, csr, W2, b2, Xb, n_waves);
    gather_fused_kernel<<<GBLOCKS, 256, 0, stream>>>(Xb, dinv, offs, csr, W3, b3, out, n_waves);
}

// Round 5
// 390.472 us; speedup vs baseline: 11.1618x; 1.0540x over previous
//
#include <hip/hip_runtime.h>

#define N_NODES 100000
#define N_EDGES 1600000

#define BKT_SHIFT 8
#define BKT_NODES 256
#define NBK ((N_NODES + BKT_NODES - 1) / BKT_NODES)      // 391 buckets
#define CHUNK 4096
#define NCHUNKS ((N_EDGES + CHUNK - 1) / CHUNK)          // 391 chunks
#define BCAP 6144                                        // LDS cap per bucket (avg 4096, ~32 sigma)

// ---------------- bucket-level histogram (391 bins) ----------------
__global__ __launch_bounds__(512) void bhist_kernel(const int* __restrict__ dst,
                                                    int* __restrict__ bhist) {
    __shared__ int h[NBK];
    for (int i = threadIdx.x; i < NBK; i += 512) h[i] = 0;
    __syncthreads();
    int stride = gridDim.x * 512;
    for (int e = blockIdx.x * 512 + threadIdx.x; e < N_EDGES; e += stride)
        atomicAdd(&h[dst[e] >> BKT_SHIFT], 1);
    __syncthreads();
    for (int i = threadIdx.x; i < NBK; i += 512) {
        int v = h[i];
        if (v) atomicAdd(&bhist[i], v);
    }
}

// ---------------- single-block scan of bucket histogram ----------------
__global__ __launch_bounds__(512) void scan_bhist_kernel(const int* __restrict__ bhist,
                                                         int* __restrict__ bbase,
                                                         int* __restrict__ bcursor) {
    __shared__ int s[512];
    int t = threadIdx.x;
    int v = (t < NBK) ? bhist[t] : 0;
    s[t] = v;
    __syncthreads();
    for (int off = 1; off < 512; off <<= 1) {
        int u = (t >= off) ? s[t - off] : 0;
        __syncthreads();
        s[t] += u;
        __syncthreads();
    }
    if (t < NBK) {
        int excl = s[t] - v;
        bbase[t] = excl;
        bcursor[t] = excl;
    }
    if (t == 0) bbase[NBK] = N_EDGES;
}

// ---------------- phase A: bin edges by 256-node bucket, coalesced runs ----------------
__global__ __launch_bounds__(512) void binA_kernel(const int* __restrict__ src,
                                                   const int* __restrict__ dst,
                                                   int* __restrict__ bcursor,
                                                   int2* __restrict__ csr_tmp) {
    __shared__ int2 staged[CHUNK];   // 32 KB
    __shared__ int delta[CHUNK];     // 16 KB
    __shared__ int hist[NBK];
    __shared__ int lcur[NBK];
    __shared__ int gdel[NBK];
    __shared__ int scan_s[512];
    int t = threadIdx.x;
    int e0 = blockIdx.x * CHUNK;
    int n = N_EDGES - e0; if (n > CHUNK) n = CHUNK;

    for (int i = t; i < NBK; i += 512) hist[i] = 0;
    __syncthreads();
    for (int i = t; i < n; i += 512) atomicAdd(&hist[dst[e0 + i] >> BKT_SHIFT], 1);
    __syncthreads();
    int v = (t < NBK) ? hist[t] : 0;
    scan_s[t] = v;
    __syncthreads();
    for (int off = 1; off < 512; off <<= 1) {
        int u = (t >= off) ? scan_s[t - off] : 0;
        __syncthreads();
        scan_s[t] += u;
        __syncthreads();
    }
    if (t < NBK) {
        int excl = scan_s[t] - v;
        lcur[t] = excl;
        int g = atomicAdd(&bcursor[t], v);  // reserve contiguous run in bucket region
        gdel[t] = g - excl;
    }
    __syncthreads();
    for (int i = t; i < n; i += 512) {
        int s = src[e0 + i];
        int d = dst[e0 + i];
        int bkt = d >> BKT_SHIFT;
        int slot = atomicAdd(&lcur[bkt], 1);
        staged[slot] = make_int2(s, d);
        delta[slot] = gdel[bkt];
    }
    __syncthreads();
    for (int p = t; p < n; p += 512) csr_tmp[delta[p] + p] = staged[p];
}

// ---------------- phase B: per-bucket hist/scan/offs/dinv + exact CSR ordering ----------------
__global__ __launch_bounds__(256) void binB_kernel(const int* __restrict__ bbase,
                                                   const int2* __restrict__ csr_tmp,
                                                   int* __restrict__ offs,
                                                   float* __restrict__ dinv,
                                                   int* __restrict__ csr) {
    __shared__ int src_s[BCAP];            // 24 KB
    __shared__ unsigned char dloc[BCAP];   // 6 KB
    __shared__ int out_s[BCAP];            // 24 KB
    __shared__ int lcnt[BKT_NODES];
    __shared__ int ss[BKT_NODES];
    __shared__ int lcur[BKT_NODES];
    int t = threadIdx.x;
    int node0 = blockIdx.x * BKT_NODES;
    int base = bbase[blockIdx.x];
    int cnt = bbase[blockIdx.x + 1] - base;
    lcnt[t] = 0;
    __syncthreads();
    bool fits = (cnt <= BCAP);
    if (fits) {
        for (int i = t; i < cnt; i += 256) {
            int2 e = csr_tmp[base + i];
            int dl = e.y - node0;
            src_s[i] = e.x;
            dloc[i] = (unsigned char)dl;
            atomicAdd(&lcnt[dl], 1);
        }
    } else {
        for (int i = t; i < cnt; i += 256) atomicAdd(&lcnt[csr_tmp[base + i].y - node0], 1);
    }
    __syncthreads();
    // local exclusive scan of the 256 per-node counts
    int v = lcnt[t];
    ss[t] = v;
    __syncthreads();
    for (int off = 1; off < 256; off <<= 1) {
        int u = (t >= off) ? ss[t - off] : 0;
        __syncthreads();
        ss[t] += u;
        __syncthreads();
    }
    int excl = ss[t] - v;
    lcur[t] = excl;
    int node = node0 + t;
    if (node < N_NODES) {
        offs[node] = base + excl;
        dinv[node] = rsqrtf((float)v + 1.0f);
    }
    if (blockIdx.x == NBK - 1 && t == 0) offs[N_NODES] = N_EDGES;
    __syncthreads();
    if (fits) {
        for (int i = t; i < cnt; i += 256) {
            int slot = atomicAdd(&lcur[dloc[i]], 1);
            out_s[slot] = src_s[i];
        }
        __syncthreads();
        for (int i = t; i < cnt; i += 256) csr[base + i] = out_s[i];
    } else {
        // statistically unreachable fallback
        for (int i = t; i < cnt; i += 256) {
            int2 e = csr_tmp[base + i];
            int slot = atomicAdd(&lcur[e.y - node0], 1);
            csr[base + slot] = e.x;
        }
    }
}

// ---------------- fused gather + GEMM epilogue ----------------
// out[n] = (sum_{s in in(n)} X[s]*dinv[s]*dinv[n] + X[n]*dinv[n]^2) @ W + b
__global__ __launch_bounds__(256) void gather_fused_kernel(
    const float* __restrict__ X, const float* __restrict__ dinv,
    const int* __restrict__ offs, const int* __restrict__ csr,
    const float* __restrict__ W, const float* __restrict__ b,
    float* __restrict__ out, int n_waves) {
    int lane = threadIdx.x & 63;
    int wid = (blockIdx.x * blockDim.x + threadIdx.x) >> 6;
    int sub = lane >> 4;       // 0..3: edge slot within wave
    int l16 = lane & 15;       // 4-channel group: channels l16*4..+3
    const float4* Xv = (const float4*)X;

    float wcol[64];            // W[k][lane] (lane = output channel)
#pragma unroll
    for (int k = 0; k < 64; k++) wcol[k] = W[k * 64 + lane];
    float blane = b[lane];

    for (int node = wid; node < N_NODES; node += n_waves) {
        float di = dinv[node];
        int beg = offs[node], end = offs[node + 1];
        float4 acc;
        if (sub == 0) {
            float4 xs = Xv[node * 16 + l16];
            float d2 = di * di;
            acc = make_float4(xs.x * d2, xs.y * d2, xs.z * d2, xs.w * d2);
        } else {
            acc = make_float4(0.f, 0.f, 0.f, 0.f);
        }
        // 4 edges in flight per wave; (src, dinv[src]) prefetched 2 deep
        int i = beg + sub;
        int sA = (i < end) ? csr[i] : 0;
        int sB = (i + 4 < end) ? csr[i + 4] : 0;
        float wA = dinv[sA];
        float wB = dinv[sB];
        while (i < end) {
            float4 vr = Xv[(size_t)sA * 16 + l16];
            int inn = i + 8;
            int sC = (inn < end) ? csr[inn] : 0;
            float wC = dinv[sC];
            float nw = wA * di;
            acc.x += vr.x * nw;
            acc.y += vr.y * nw;
            acc.z += vr.z * nw;
            acc.w += vr.w * nw;
            sA = sB; wA = wB; sB = sC; wB = wC; i += 4;
        }
        // reduce across the 4 subs
        acc.x += __shfl_xor(acc.x, 16, 64); acc.y += __shfl_xor(acc.y, 16, 64);
        acc.z += __shfl_xor(acc.z, 16, 64); acc.w += __shfl_xor(acc.w, 16, 64);
        acc.x += __shfl_xor(acc.x, 32, 64); acc.y += __shfl_xor(acc.y, 32, 64);
        acc.z += __shfl_xor(acc.z, 32, 64); acc.w += __shfl_xor(acc.w, 32, 64);
        // redistribute: lane c takes channel c
        int srcl = lane >> 2;
        float t0 = __shfl(acc.x, srcl, 64);
        float t1 = __shfl(acc.y, srcl, 64);
        float t2 = __shfl(acc.z, srcl, 64);
        float t3 = __shfl(acc.w, srcl, 64);
        int comp = lane & 3;
        float a = (comp == 0) ? t0 : (comp == 1) ? t1 : (comp == 2) ? t2 : t3;
        // matvec epilogue
        float r = blane;
#pragma unroll
        for (int k = 0; k < 64; k++) {
            float ak = __int_as_float(__builtin_amdgcn_readlane(__float_as_int(a), k));
            r += ak * wcol[k];
        }
        out[(size_t)node * 64 + lane] = r;
    }
}

extern "C" void kernel_launch(void* const* d_in, const int* in_sizes, int n_in,
                              void* d_out, int out_size, void* d_ws, size_t ws_size,
                              hipStream_t stream) {
    const float* emb = (const float*)d_in[0];
    const int* edge  = (const int*)d_in[1];
    const float* W1 = (const float*)d_in[2];
    const float* b1 = (const float*)d_in[3];
    const float* W2 = (const float*)d_in[4];
    const float* b2 = (const float*)d_in[5];
    const float* W3 = (const float*)d_in[6];
    const float* b3 = (const float*)d_in[7];
    float* out = (float*)d_out;

    const int* src = edge;
    const int* dst = edge + N_EDGES;

    char* ws = (char*)d_ws;
    size_t off = 0;
    int* bhist = (int*)(ws + off);      off += 2048;
    int* bbase = (int*)(ws + off);      off += 2048;     // NBK+1
    int* bcursor = (int*)(ws + off);    off += 2048;
    int* offs = (int*)(ws + off);       off += 400128;   // N_NODES+1
    float* dinv = (float*)(ws + off);   off += 400128;
    int2* csr_tmp = (int2*)(ws + off);  off += 12800128;
    int* csr = (int*)(ws + off);        off += 6400128;
    float* Xa = (float*)(ws + off);     off += 25600000;
    float* Xb = (float*)(ws + off);     // 25.6 MB

    // ---- CSR build (shared by all 3 layers) ----
    hipMemsetAsync(bhist, 0, NBK * sizeof(int), stream);
    bhist_kernel<<<64, 512, 0, stream>>>(dst, bhist);
    scan_bhist_kernel<<<1, 512, 0, stream>>>(bhist, bbase, bcursor);
    binA_kernel<<<NCHUNKS, 512, 0, stream>>>(src, dst, bcursor, csr_tmp);
    binB_kernel<<<NBK, 256, 0, stream>>>(bbase, csr_tmp, offs, dinv, csr);

    const int GBLOCKS = 2048;                 // 8192 waves = full wave-slot capacity
    const int n_waves = GBLOCKS * 256 / 64;

    gather_fused_kernel<<<GBLOCKS, 256, 0, stream>>>(emb, dinv, offs, csr, W1, b1, Xa, n_waves);
    gather_fused_kernel<<<GBLOCKS, 256, 0, stream>>>(Xa, dinv, offs, csr, W2, b2, Xb, n_waves);
    gather_fused_kernel<<<GBLOCKS, 256, 0, stream>>>(Xb, dinv, offs, csr, W3, b3, out, n_waves);
}

// Round 6
// 388.080 us; speedup vs baseline: 11.2306x; 1.0062x over previous
//
#include <hip/hip_runtime.h>

#define N_NODES 100000
#define N_EDGES 1600000

#define BKT_SHIFT 8
#define BKT_NODES 256
#define NBK ((N_NODES + BKT_NODES - 1) / BKT_NODES)      // 391 buckets
#define CHUNK 4096
#define NCHUNKS ((N_EDGES + CHUNK - 1) / CHUNK)          // 391 chunks
#define BCAP 6144                                        // LDS cap per bucket (avg 4096, ~32 sigma)

// ---------------- bucket-level histogram (391 bins) ----------------
__global__ __launch_bounds__(512) void bhist_kernel(const int* __restrict__ dst,
                                                    int* __restrict__ bhist) {
    __shared__ int h[NBK];
    for (int i = threadIdx.x; i < NBK; i += 512) h[i] = 0;
    __syncthreads();
    int stride = gridDim.x * 512;
    for (int e = blockIdx.x * 512 + threadIdx.x; e < N_EDGES; e += stride)
        atomicAdd(&h[dst[e] >> BKT_SHIFT], 1);
    __syncthreads();
    for (int i = threadIdx.x; i < NBK; i += 512) {
        int v = h[i];
        if (v) atomicAdd(&bhist[i], v);
    }
}

// ---------------- single-block scan of bucket histogram ----------------
__global__ __launch_bounds__(512) void scan_bhist_kernel(const int* __restrict__ bhist,
                                                         int* __restrict__ bbase,
                                                         int* __restrict__ bcursor) {
    __shared__ int s[512];
    int t = threadIdx.x;
    int v = (t < NBK) ? bhist[t] : 0;
    s[t] = v;
    __syncthreads();
    for (int off = 1; off < 512; off <<= 1) {
        int u = (t >= off) ? s[t - off] : 0;
        __syncthreads();
        s[t] += u;
        __syncthreads();
    }
    if (t < NBK) {
        int excl = s[t] - v;
        bbase[t] = excl;
        bcursor[t] = excl;
    }
    if (t == 0) bbase[NBK] = N_EDGES;
}

// ---------------- phase A: bin edges by 256-node bucket, coalesced runs ----------------
__global__ __launch_bounds__(512) void binA_kernel(const int* __restrict__ src,
                                                   const int* __restrict__ dst,
                                                   int* __restrict__ bcursor,
                                                   int2* __restrict__ csr_tmp) {
    __shared__ int2 staged[CHUNK];   // 32 KB
    __shared__ int delta[CHUNK];     // 16 KB
    __shared__ int hist[NBK];
    __shared__ int lcur[NBK];
    __shared__ int gdel[NBK];
    __shared__ int scan_s[512];
    int t = threadIdx.x;
    int e0 = blockIdx.x * CHUNK;
    int n = N_EDGES - e0; if (n > CHUNK) n = CHUNK;

    for (int i = t; i < NBK; i += 512) hist[i] = 0;
    __syncthreads();
    for (int i = t; i < n; i += 512) atomicAdd(&hist[dst[e0 + i] >> BKT_SHIFT], 1);
    __syncthreads();
    int v = (t < NBK) ? hist[t] : 0;
    scan_s[t] = v;
    __syncthreads();
    for (int off = 1; off < 512; off <<= 1) {
        int u = (t >= off) ? scan_s[t - off] : 0;
        __syncthreads();
        scan_s[t] += u;
        __syncthreads();
    }
    if (t < NBK) {
        int excl = scan_s[t] - v;
        lcur[t] = excl;
        int g = atomicAdd(&bcursor[t], v);  // reserve contiguous run in bucket region
        gdel[t] = g - excl;
    }
    __syncthreads();
    for (int i = t; i < n; i += 512) {
        int s = src[e0 + i];
        int d = dst[e0 + i];
        int bkt = d >> BKT_SHIFT;
        int slot = atomicAdd(&lcur[bkt], 1);
        staged[slot] = make_int2(s, d);
        delta[slot] = gdel[bkt];
    }
    __syncthreads();
    for (int p = t; p < n; p += 512) csr_tmp[delta[p] + p] = staged[p];
}

// ---------------- phase B: per-bucket hist/scan/offs/dinv + exact CSR ordering ----------------
__global__ __launch_bounds__(256) void binB_kernel(const int* __restrict__ bbase,
                                                   const int2* __restrict__ csr_tmp,
                                                   int* __restrict__ offs,
                                                   float* __restrict__ dinv,
                                                   int* __restrict__ csr) {
    __shared__ int src_s[BCAP];            // 24 KB
    __shared__ unsigned char dloc[BCAP];   // 6 KB
    __shared__ int out_s[BCAP];            // 24 KB
    __shared__ int lcnt[BKT_NODES];
    __shared__ int ss[BKT_NODES];
    __shared__ int lcur[BKT_NODES];
    int t = threadIdx.x;
    int node0 = blockIdx.x * BKT_NODES;
    int base = bbase[blockIdx.x];
    int cnt = bbase[blockIdx.x + 1] - base;
    lcnt[t] = 0;
    __syncthreads();
    bool fits = (cnt <= BCAP);
    if (fits) {
        for (int i = t; i < cnt; i += 256) {
            int2 e = csr_tmp[base + i];
            int dl = e.y - node0;
            src_s[i] = e.x;
            dloc[i] = (unsigned char)dl;
            atomicAdd(&lcnt[dl], 1);
        }
    } else {
        for (int i = t; i < cnt; i += 256) atomicAdd(&lcnt[csr_tmp[base + i].y - node0], 1);
    }
    __syncthreads();
    // local exclusive scan of the 256 per-node counts
    int v = lcnt[t];
    ss[t] = v;
    __syncthreads();
    for (int off = 1; off < 256; off <<= 1) {
        int u = (t >= off) ? ss[t - off] : 0;
        __syncthreads();
        ss[t] += u;
        __syncthreads();
    }
    int excl = ss[t] - v;
    lcur[t] = excl;
    int node = node0 + t;
    if (node < N_NODES) {
        offs[node] = base + excl;
        dinv[node] = rsqrtf((float)v + 1.0f);
    }
    if (blockIdx.x == NBK - 1 && t == 0) offs[N_NODES] = N_EDGES;
    __syncthreads();
    if (fits) {
        for (int i = t; i < cnt; i += 256) {
            int slot = atomicAdd(&lcur[dloc[i]], 1);
            out_s[slot] = src_s[i];
        }
        __syncthreads();
        for (int i = t; i < cnt; i += 256) csr[base + i] = out_s[i];
    } else {
        // statistically unreachable fallback
        for (int i = t; i < cnt; i += 256) {
            int2 e = csr_tmp[base + i];
            int slot = atomicAdd(&lcur[e.y - node0], 1);
            csr[base + slot] = e.x;
        }
    }
}

// ---------------- prescale: Xs = X * dinv (row-wise) ----------------
__global__ __launch_bounds__(256) void prescale_kernel(const float* __restrict__ X,
                                                       const float* __restrict__ dinv,
                                                       float* __restrict__ Xs) {
    int i = blockIdx.x * 256 + threadIdx.x;  // float4 index
    if (i < N_NODES * 16) {
        float4 v = ((const float4*)X)[i];
        float d = dinv[i >> 4];
        float4 o = make_float4(v.x * d, v.y * d, v.z * d, v.w * d);
        ((float4*)Xs)[i] = o;
    }
}

// ---------------- fused gather + GEMM epilogue (pre-scaled features) ----------------
// in:  Xs[s] = X[s]*dinv[s]
// A[n] = dinv[n] * (Xs[n] + sum_{s in in(n)} Xs[s])
// r    = A[n] @ W + b        (layer output)
// out[n] = prescale_out ? r*dinv[n] : r
__global__ __launch_bounds__(256) void gather_fused_kernel(
    const float* __restrict__ Xs, const float* __restrict__ dinv,
    const int* __restrict__ offs, const int* __restrict__ csr,
    const float* __restrict__ W, const float* __restrict__ b,
    float* __restrict__ out, int n_waves, int prescale_out) {
    int lane = threadIdx.x & 63;
    int wid = (blockIdx.x * blockDim.x + threadIdx.x) >> 6;
    int sub = lane >> 4;       // 0..3: edge slot within wave
    int l16 = lane & 15;       // 4-channel group: channels l16*4..+3
    const float4* Xv = (const float4*)Xs;

    float blane = b[lane];

    for (int node = wid; node < N_NODES; node += n_waves) {
        float di = dinv[node];
        int beg = offs[node], end = offs[node + 1];
        float4 acc;
        if (sub == 0) {
            acc = Xv[node * 16 + l16];          // own (pre-scaled) row
        } else {
            acc = make_float4(0.f, 0.f, 0.f, 0.f);
        }
        // pure-add edge loop: csr prefetch 2-deep, row prefetch 2-deep
        int i = beg + sub;
        int sA = (i < end) ? csr[i] : 0;
        int sB = (i + 4 < end) ? csr[i + 4] : 0;
        float4 rA = Xv[(size_t)sA * 16 + l16];
        while (i < end) {
            int sC = (i + 8 < end) ? csr[i + 8] : 0;
            float4 rB = Xv[(size_t)sB * 16 + l16];
            acc.x += rA.x; acc.y += rA.y; acc.z += rA.z; acc.w += rA.w;
            rA = rB; sB = sC; i += 4;
        }
        // reduce across the 4 subs
        acc.x += __shfl_xor(acc.x, 16, 64); acc.y += __shfl_xor(acc.y, 16, 64);
        acc.z += __shfl_xor(acc.z, 16, 64); acc.w += __shfl_xor(acc.w, 16, 64);
        acc.x += __shfl_xor(acc.x, 32, 64); acc.y += __shfl_xor(acc.y, 32, 64);
        acc.z += __shfl_xor(acc.z, 32, 64); acc.w += __shfl_xor(acc.w, 32, 64);
        // redistribute: lane c takes channel c
        int srcl = lane >> 2;
        float t0 = __shfl(acc.x, srcl, 64);
        float t1 = __shfl(acc.y, srcl, 64);
        float t2 = __shfl(acc.z, srcl, 64);
        float t3 = __shfl(acc.w, srcl, 64);
        int comp = lane & 3;
        float a = (comp == 0) ? t0 : (comp == 1) ? t1 : (comp == 2) ? t2 : t3;
        a *= di;  // A[n] channel for this lane
        // matvec epilogue: r[c] = b[c] + sum_k a_k W[k][c]
        float r = blane;
#pragma unroll
        for (int k = 0; k < 64; k++) {
            float ak = __int_as_float(__builtin_amdgcn_readlane(__float_as_int(a), k));
            r += ak * W[k * 64 + lane];
        }
        if (prescale_out) r *= di;
        out[(size_t)node * 64 + lane] = r;
    }
}

extern "C" void kernel_launch(void* const* d_in, const int* in_sizes, int n_in,
                              void* d_out, int out_size, void* d_ws, size_t ws_size,
                              hipStream_t stream) {
    const float* emb = (const float*)d_in[0];
    const int* edge  = (const int*)d_in[1];
    const float* W1 = (const float*)d_in[2];
    const float* b1 = (const float*)d_in[3];
    const float* W2 = (const float*)d_in[4];
    const float* b2 = (const float*)d_in[5];
    const float* W3 = (const float*)d_in[6];
    const float* b3 = (const float*)d_in[7];
    float* out = (float*)d_out;

    const int* src = edge;
    const int* dst = edge + N_EDGES;

    char* ws = (char*)d_ws;
    size_t off = 0;
    int* bhist = (int*)(ws + off);      off += 2048;
    int* bbase = (int*)(ws + off);      off += 2048;     // NBK+1
    int* bcursor = (int*)(ws + off);    off += 2048;
    int* offs = (int*)(ws + off);       off += 400128;   // N_NODES+1
    float* dinv = (float*)(ws + off);   off += 400128;
    int2* csr_tmp = (int2*)(ws + off);  off += 12800128;
    int* csr = (int*)(ws + off);        off += 6400128;
    float* Xa = (float*)(ws + off);     off += 25600000;
    float* Xb = (float*)(ws + off);     // 25.6 MB

    // ---- CSR build (shared by all 3 layers) ----
    hipMemsetAsync(bhist, 0, NBK * sizeof(int), stream);
    bhist_kernel<<<64, 512, 0, stream>>>(dst, bhist);
    scan_bhist_kernel<<<1, 512, 0, stream>>>(bhist, bbase, bcursor);
    binA_kernel<<<NCHUNKS, 512, 0, stream>>>(src, dst, bcursor, csr_tmp);
    binB_kernel<<<NBK, 256, 0, stream>>>(bbase, csr_tmp, offs, dinv, csr);

    // Xs0 = emb * dinv  -> Xa
    prescale_kernel<<<(N_NODES * 16 + 255) / 256, 256, 0, stream>>>(emb, dinv, Xa);

    const int GBLOCKS = 2048;                 // 8192 waves = full wave-slot capacity
    const int n_waves = GBLOCKS * 256 / 64;

    // layer 1: Xa(pre-scaled emb) -> Xb (pre-scaled layer-1 output)
    gather_fused_kernel<<<GBLOCKS, 256, 0, stream>>>(Xa, dinv, offs, csr, W1, b1, Xb, n_waves, 1);
    // layer 2: Xb -> Xa (pre-scaled layer-2 output)
    gather_fused_kernel<<<GBLOCKS, 256, 0, stream>>>(Xb, dinv, offs, csr, W2, b2, Xa, n_waves, 1);
    // layer 3: Xa -> out (plain)
    gather_fused_kernel<<<GBLOCKS, 256, 0, stream>>>(Xa, dinv, offs, csr, W3, b3, out, n_waves, 0);
}

// Round 7
// 384.618 us; speedup vs baseline: 11.3317x; 1.0090x over previous
//
#include <hip/hip_runtime.h>

#define N_NODES 100000
#define N_EDGES 1600000

#define BKT_SHIFT 8
#define BKT_NODES 256
#define NBK ((N_NODES + BKT_NODES - 1) / BKT_NODES)      // 391 buckets
#define CHUNK 4096
#define NCHUNKS ((N_EDGES + CHUNK - 1) / CHUNK)          // 391 chunks
#define BCAP 6144                                        // LDS cap per bucket (avg 4096, ~32 sigma)

// ---------------- bucket-level histogram (391 bins) ----------------
__global__ __launch_bounds__(512) void bhist_kernel(const int* __restrict__ dst,
                                                    int* __restrict__ bhist) {
    __shared__ int h[NBK];
    for (int i = threadIdx.x; i < NBK; i += 512) h[i] = 0;
    __syncthreads();
    int stride = gridDim.x * 512;
    for (int e = blockIdx.x * 512 + threadIdx.x; e < N_EDGES; e += stride)
        atomicAdd(&h[dst[e] >> BKT_SHIFT], 1);
    __syncthreads();
    for (int i = threadIdx.x; i < NBK; i += 512) {
        int v = h[i];
        if (v) atomicAdd(&bhist[i], v);
    }
}

// ---------------- single-block scan of bucket histogram ----------------
__global__ __launch_bounds__(512) void scan_bhist_kernel(const int* __restrict__ bhist,
                                                         int* __restrict__ bbase,
                                                         int* __restrict__ bcursor) {
    __shared__ int s[512];
    int t = threadIdx.x;
    int v = (t < NBK) ? bhist[t] : 0;
    s[t] = v;
    __syncthreads();
    for (int off = 1; off < 512; off <<= 1) {
        int u = (t >= off) ? s[t - off] : 0;
        __syncthreads();
        s[t] += u;
        __syncthreads();
    }
    if (t < NBK) {
        int excl = s[t] - v;
        bbase[t] = excl;
        bcursor[t] = excl;
    }
    if (t == 0) bbase[NBK] = N_EDGES;
}

// ---------------- phase A: bin edges by 256-node bucket, coalesced runs ----------------
__global__ __launch_bounds__(512) void binA_kernel(const int* __restrict__ src,
                                                   const int* __restrict__ dst,
                                                   int* __restrict__ bcursor,
                                                   int2* __restrict__ csr_tmp) {
    __shared__ int2 staged[CHUNK];   // 32 KB
    __shared__ int delta[CHUNK];     // 16 KB
    __shared__ int hist[NBK];
    __shared__ int lcur[NBK];
    __shared__ int gdel[NBK];
    __shared__ int scan_s[512];
    int t = threadIdx.x;
    int e0 = blockIdx.x * CHUNK;
    int n = N_EDGES - e0; if (n > CHUNK) n = CHUNK;

    for (int i = t; i < NBK; i += 512) hist[i] = 0;
    __syncthreads();
    for (int i = t; i < n; i += 512) atomicAdd(&hist[dst[e0 + i] >> BKT_SHIFT], 1);
    __syncthreads();
    int v = (t < NBK) ? hist[t] : 0;
    scan_s[t] = v;
    __syncthreads();
    for (int off = 1; off < 512; off <<= 1) {
        int u = (t >= off) ? scan_s[t - off] : 0;
        __syncthreads();
        scan_s[t] += u;
        __syncthreads();
    }
    if (t < NBK) {
        int excl = scan_s[t] - v;
        lcur[t] = excl;
        int g = atomicAdd(&bcursor[t], v);  // reserve contiguous run in bucket region
        gdel[t] = g - excl;
    }
    __syncthreads();
    for (int i = t; i < n; i += 512) {
        int s = src[e0 + i];
        int d = dst[e0 + i];
        int bkt = d >> BKT_SHIFT;
        int slot = atomicAdd(&lcur[bkt], 1);
        staged[slot] = make_int2(s, d);
        delta[slot] = gdel[bkt];
    }
    __syncthreads();
    for (int p = t; p < n; p += 512) csr_tmp[delta[p] + p] = staged[p];
}

// ---------------- phase B: per-bucket hist/scan/offs/dinv + exact CSR ordering ----------------
__global__ __launch_bounds__(256) void binB_kernel(const int* __restrict__ bbase,
                                                   const int2* __restrict__ csr_tmp,
                                                   int* __restrict__ offs,
                                                   float* __restrict__ dinv,
                                                   int* __restrict__ csr) {
    __shared__ int src_s[BCAP];            // 24 KB
    __shared__ unsigned char dloc[BCAP];   // 6 KB
    __shared__ int out_s[BCAP];            // 24 KB
    __shared__ int lcnt[BKT_NODES];
    __shared__ int ss[BKT_NODES];
    __shared__ int lcur[BKT_NODES];
    int t = threadIdx.x;
    int node0 = blockIdx.x * BKT_NODES;
    int base = bbase[blockIdx.x];
    int cnt = bbase[blockIdx.x + 1] - base;
    lcnt[t] = 0;
    __syncthreads();
    bool fits = (cnt <= BCAP);
    if (fits) {
        for (int i = t; i < cnt; i += 256) {
            int2 e = csr_tmp[base + i];
            int dl = e.y - node0;
            src_s[i] = e.x;
            dloc[i] = (unsigned char)dl;
            atomicAdd(&lcnt[dl], 1);
        }
    } else {
        for (int i = t; i < cnt; i += 256) atomicAdd(&lcnt[csr_tmp[base + i].y - node0], 1);
    }
    __syncthreads();
    int v = lcnt[t];
    ss[t] = v;
    __syncthreads();
    for (int off = 1; off < 256; off <<= 1) {
        int u = (t >= off) ? ss[t - off] : 0;
        __syncthreads();
        ss[t] += u;
        __syncthreads();
    }
    int excl = ss[t] - v;
    lcur[t] = excl;
    int node = node0 + t;
    if (node < N_NODES) {
        offs[node] = base + excl;
        dinv[node] = rsqrtf((float)v + 1.0f);
    }
    if (blockIdx.x == NBK - 1 && t == 0) offs[N_NODES] = N_EDGES;
    __syncthreads();
    if (fits) {
        for (int i = t; i < cnt; i += 256) {
            int slot = atomicAdd(&lcur[dloc[i]], 1);
            out_s[slot] = src_s[i];
        }
        __syncthreads();
        for (int i = t; i < cnt; i += 256) csr[base + i] = out_s[i];
    } else {
        for (int i = t; i < cnt; i += 256) {
            int2 e = csr_tmp[base + i];
            int slot = atomicAdd(&lcur[e.y - node0], 1);
            csr[base + slot] = e.x;
        }
    }
}

// ---------------- prescale: Xs = X * dinv (row-wise) ----------------
__global__ __launch_bounds__(256) void prescale_kernel(const float* __restrict__ X,
                                                       const float* __restrict__ dinv,
                                                       float* __restrict__ Xs) {
    int i = blockIdx.x * 256 + threadIdx.x;  // float4 index
    if (i < N_NODES * 16) {
        float4 v = ((const float4*)X)[i];
        float d = dinv[i >> 4];
        float4 o = make_float4(v.x * d, v.y * d, v.z * d, v.w * d);
        ((float4*)Xs)[i] = o;
    }
}

// ---------------- fused gather + GEMM epilogue (pre-scaled, dual-stream MLP) ----------------
// in:  Xs[s] = X[s]*dinv[s]
// A[n] = dinv[n] * (Xs[n] + sum_{s in in(n)} Xs[s])
// r    = A[n] @ W + b ; out = prescale_out ? r*dinv[n] : r
__global__ __launch_bounds__(256) void gather_fused_kernel(
    const float* __restrict__ Xs, const float* __restrict__ dinv,
    const int* __restrict__ offs, const int* __restrict__ csr,
    const float* __restrict__ W, const float* __restrict__ b,
    float* __restrict__ out, int n_waves, int prescale_out) {
    int lane = threadIdx.x & 63;
    int wid = (blockIdx.x * blockDim.x + threadIdx.x) >> 6;
    int sub = lane >> 4;       // 0..3: edge slot within 4-group
    int l16 = lane & 15;       // 4-channel group
    const float4* Xv = (const float4*)Xs;

    float blane = b[lane];

    for (int node = wid; node < N_NODES; node += n_waves) {
        float di = dinv[node];
        int beg = offs[node], end = offs[node + 1];
        float4 acc;
        if (sub == 0) {
            acc = Xv[node * 16 + l16];          // own (pre-scaled) row
        } else {
            acc = make_float4(0.f, 0.f, 0.f, 0.f);
        }
        // dual-stream edge loop: 8 edges/iteration, two independent 1KB row
        // loads in flight + 2 csr prefetches (depth-2 per stream)
        int i = beg + sub;                       // stream0: i, i+8, ...  stream1: i+4, i+12, ...
        int sA0 = (i      < end) ? csr[i]      : 0;
        int sA1 = (i + 4  < end) ? csr[i + 4]  : 0;
        int sB0 = (i + 8  < end) ? csr[i + 8]  : 0;
        int sB1 = (i + 12 < end) ? csr[i + 12] : 0;
        float4 rA0 = Xv[(size_t)sA0 * 16 + l16];
        float4 rA1 = Xv[(size_t)sA1 * 16 + l16];
        while (i < end) {
            float4 rB0 = Xv[(size_t)sB0 * 16 + l16];
            float4 rB1 = Xv[(size_t)sB1 * 16 + l16];
            int sC0 = (i + 16 < end) ? csr[i + 16] : 0;
            int sC1 = (i + 20 < end) ? csr[i + 20] : 0;
            float m1 = (i + 4 < end) ? 1.0f : 0.0f;   // stream0 add is covered by loop cond
            acc.x += rA0.x; acc.y += rA0.y; acc.z += rA0.z; acc.w += rA0.w;
            acc.x = fmaf(rA1.x, m1, acc.x);
            acc.y = fmaf(rA1.y, m1, acc.y);
            acc.z = fmaf(rA1.z, m1, acc.z);
            acc.w = fmaf(rA1.w, m1, acc.w);
            rA0 = rB0; rA1 = rB1;
            sB0 = sC0; sB1 = sC1;
            i += 8;
        }
        // reduce across the 4 subs
        acc.x += __shfl_xor(acc.x, 16, 64); acc.y += __shfl_xor(acc.y, 16, 64);
        acc.z += __shfl_xor(acc.z, 16, 64); acc.w += __shfl_xor(acc.w, 16, 64);
        acc.x += __shfl_xor(acc.x, 32, 64); acc.y += __shfl_xor(acc.y, 32, 64);
        acc.z += __shfl_xor(acc.z, 32, 64); acc.w += __shfl_xor(acc.w, 32, 64);
        // redistribute: lane c takes channel c
        int srcl = lane >> 2;
        float t0 = __shfl(acc.x, srcl, 64);
        float t1 = __shfl(acc.y, srcl, 64);
        float t2 = __shfl(acc.z, srcl, 64);
        float t3 = __shfl(acc.w, srcl, 64);
        int comp = lane & 3;
        float a = (comp == 0) ? t0 : (comp == 1) ? t1 : (comp == 2) ? t2 : t3;
        a *= di;
        // matvec epilogue
        float r = blane;
#pragma unroll
        for (int k = 0; k < 64; k++) {
            float ak = __int_as_float(__builtin_amdgcn_readlane(__float_as_int(a), k));
            r += ak * W[k * 64 + lane];
        }
        if (prescale_out) r *= di;
        out[(size_t)node * 64 + lane] = r;
    }
}

extern "C" void kernel_launch(void* const* d_in, const int* in_sizes, int n_in,
                              void* d_out, int out_size, void* d_ws, size_t ws_size,
                              hipStream_t stream) {
    const float* emb = (const float*)d_in[0];
    const int* edge  = (const int*)d_in[1];
    const float* W1 = (const float*)d_in[2];
    const float* b1 = (const float*)d_in[3];
    const float* W2 = (const float*)d_in[4];
    const float* b2 = (const float*)d_in[5];
    const float* W3 = (const float*)d_in[6];
    const float* b3 = (const float*)d_in[7];
    float* out = (float*)d_out;

    const int* src = edge;
    const int* dst = edge + N_EDGES;

    char* ws = (char*)d_ws;
    size_t off = 0;
    int* bhist = (int*)(ws + off);      off += 2048;
    int* bbase = (int*)(ws + off);      off += 2048;     // NBK+1
    int* bcursor = (int*)(ws + off);    off += 2048;
    int* offs = (int*)(ws + off);       off += 400128;   // N_NODES+1
    float* dinv = (float*)(ws + off);   off += 400128;
    int2* csr_tmp = (int2*)(ws + off);  off += 12800128;
    int* csr = (int*)(ws + off);        off += 6400128;
    float* Xa = (float*)(ws + off);     off += 25600000;
    float* Xb = (float*)(ws + off);     // 25.6 MB

    // ---- CSR build (shared by all 3 layers) ----
    hipMemsetAsync(bhist, 0, NBK * sizeof(int), stream);
    bhist_kernel<<<64, 512, 0, stream>>>(dst, bhist);
    scan_bhist_kernel<<<1, 512, 0, stream>>>(bhist, bbase, bcursor);
    binA_kernel<<<NCHUNKS, 512, 0, stream>>>(src, dst, bcursor, csr_tmp);
    binB_kernel<<<NBK, 256, 0, stream>>>(bbase, csr_tmp, offs, dinv, csr);

    // Xs0 = emb * dinv  -> Xa
    prescale_kernel<<<(N_NODES * 16 + 255) / 256, 256, 0, stream>>>(emb, dinv, Xa);

    const int GBLOCKS = 2048;                 // 8192 waves
    const int n_waves = GBLOCKS * 256 / 64;

    gather_fused_kernel<<<GBLOCKS, 256, 0, stream>>>(Xa, dinv, offs, csr, W1, b1, Xb, n_waves, 1);
    gather_fused_kernel<<<GBLOCKS, 256, 0, stream>>>(Xb, dinv, offs, csr, W2, b2, Xa, n_waves, 1);
    gather_fused_kernel<<<GBLOCKS, 256, 0, stream>>>(Xa, dinv, offs, csr, W3, b3, out, n_waves, 0);
}